// Round 5
// baseline (255.246 us; speedup 1.0000x reference)
//
#include <hip/hip_runtime.h>
#include <hip/hip_bf16.h>
#include <stdint.h>

#define HW_ 4096

typedef float f32x4 __attribute__((ext_vector_type(4)));
typedef short bf16x8 __attribute__((ext_vector_type(8)));

__device__ __forceinline__ unsigned short f2bf(float f) {
  __hip_bfloat16 h = __float2bfloat16(f);
  return *reinterpret_cast<unsigned short*>(&h);
}
__device__ __forceinline__ float bf2f(unsigned short u) {
  union { unsigned int i; float f; } c; c.i = ((unsigned int)u) << 16; return c.f;
}
__device__ __forceinline__ float sigmoidf_(float x) { return 1.f / (1.f + __expf(-x)); }

__device__ __forceinline__ void glds16(const void* g, void* l) {
  __builtin_amdgcn_global_load_lds(
      (const __attribute__((address_space(1))) unsigned int*)g,
      (__attribute__((address_space(3))) unsigned int*)l, 16, 0, 0);
}

// ---- 1. single pass over x: per-(b,c) partial mean/max + bf16 transpose to [b][hw][c] ----
__global__ void k_pre(const float* __restrict__ x, unsigned short* __restrict__ xtr,
                      float* __restrict__ psum, float* __restrict__ pmax) {
  int hwb = blockIdx.x;  // 64 hw per block
  int cb = blockIdx.y;   // 64 c per block
  int b = blockIdx.z;
  int t = threadIdx.x;
  __shared__ unsigned short lt[64][66];
  __shared__ float sv[64][65];
  int w = t >> 6, hw_l = t & 63;
#pragma unroll
  for (int i = 0; i < 16; ++i) {
    int c_l = i * 4 + w;
    int c = cb * 64 + c_l;
    float v = x[(((size_t)b * 256 + c) << 12) + hwb * 64 + hw_l];
    lt[hw_l][c_l] = f2bf(v);
    sv[c_l][hw_l] = v;
  }
  __syncthreads();
  // per-channel partials: 4 threads per channel, 16 hw each, then 2-step shuffle
  {
    int c_l = t >> 2, q = t & 3;
    float s16 = 0.f, m16 = -3.4e38f;
#pragma unroll
    for (int j = 0; j < 16; ++j) {
      float vv = sv[c_l][q * 16 + j];
      s16 += vv; m16 = fmaxf(m16, vv);
    }
    s16 += __shfl_xor(s16, 1); s16 += __shfl_xor(s16, 2);
    m16 = fmaxf(m16, __shfl_xor(m16, 1)); m16 = fmaxf(m16, __shfl_xor(m16, 2));
    if (q == 0) {
      int c = cb * 64 + c_l;
      psum[(((size_t)b * 256 + c) << 6) + hwb] = s16;
      pmax[(((size_t)b * 256 + c) << 6) + hwb] = m16;
    }
  }
#pragma unroll
  for (int i = 0; i < 8; ++i) {
    int fp = t + i * 256;
    int hw2 = fp >> 5;
    int cp = (fp & 31) * 2;
    unsigned int u = (unsigned int)lt[hw2][cp] | ((unsigned int)lt[hw2][cp + 1] << 16);
    *reinterpret_cast<unsigned int*>(xtr + (((size_t)b * 4096 + hwb * 64 + hw2) << 8) + cb * 64 + cp) = u;
  }
}

// ---- 2. small per-batch math (+ zero BN accumulators + zero page) ----
__global__ void k_tiny(const float* __restrict__ psum, const float* __restrict__ pmax,
                       const float* __restrict__ aw3, const float* __restrict__ Wout,
                       const float* __restrict__ Wk, const float* __restrict__ lw3,
                       const float* __restrict__ lbia, const float* __restrict__ mw1,
                       const float* __restrict__ mw2,
                       float* __restrict__ in_att, float* __restrict__ out_att,
                       float* __restrict__ katt, float* __restrict__ sc,
                       float* __restrict__ sums, float* __restrict__ zerob) {
  int b = blockIdx.x, t = threadIdx.x;
  __shared__ float g[256], tt[256], red[256], hsum[16], ksm[4], mx[128];
  {
    const float* pp = psum + ((size_t)(b * 256 + t) << 6);
    const float* pm = pmax + ((size_t)(b * 256 + t) << 6);
    float s = 0.f, m = -3.4e38f;
    for (int j = 0; j < 64; ++j) { s += pp[j]; m = fmaxf(m, pm[j]); }
    g[t] = s * (1.f / 4096.f);
    if (t >= 128) mx[t - 128] = m;
  }
  if (b == 0) {
    sums[t] = 0.f; sums[256 + t] = 0.f;
    if (t < 16) zerob[t] = 0.f;
  }
  __syncthreads();
  float c0 = aw3[0], c1 = aw3[1], c2 = aw3[2];
  float tv = c1 * g[t];
  if (t > 0) tv += c0 * g[t - 1];
  if (t < 255) tv += c2 * g[t + 1];
  tt[t] = tv;
  in_att[b * 256 + t] = sigmoidf_(tv);
  __syncthreads();
  {
    float d = 0.f;
    const float* wr = Wout + (size_t)t * 256;
    for (int c = 0; c < 256; ++c) d += tt[c] * wr[c];
    out_att[b * 256 + t] = sigmoidf_(d);
  }
  int k = t >> 6, lane = t & 63;
  {
    float pk = 0.f;
    for (int c = lane; c < 256; c += 64) pk += tt[c] * Wk[k * 256 + c];
    red[t] = pk; __syncthreads();
    for (int off = 32; off > 0; off >>= 1) {
      if (lane < off) red[t] += red[t + off];
      __syncthreads();
    }
    if (t == 0) {
      float l0 = red[0], l1 = red[64], l2 = red[128], l3 = red[192];
      float mm = fmaxf(fmaxf(l0, l1), fmaxf(l2, l3));
      float e0 = __expf(l0 - mm), e1 = __expf(l1 - mm), e2 = __expf(l2 - mm), e3 = __expf(l3 - mm);
      float inv = 1.f / (e0 + e1 + e2 + e3);
      ksm[0] = e0 * inv; ksm[1] = e1 * inv; ksm[2] = e2 * inv; ksm[3] = e3 * inv;
    }
    __syncthreads();
    if (t < 4) katt[b * 4 + t] = ksm[t];
  }
  if (t < 128) {
    float a0 = lw3[0], a1 = lw3[1], a2 = lw3[2];
    float sv = a1 * g[t] + lbia[0];
    if (t > 0) sv += a0 * g[t - 1];
    if (t < 127) sv += a2 * g[t + 1];
    sc[b * 256 + t] = sigmoidf_(sv);
  }
  __syncthreads();
  if (t < 16) {
    float d1 = 0.f, d2 = 0.f;
    const float* w1r = mw1 + t * 128;
    for (int j = 0; j < 128; ++j) { d1 += mx[j] * w1r[j]; d2 += g[128 + j] * w1r[j]; }
    hsum[t] = fmaxf(d1, 0.f) + fmaxf(d2, 0.f);
  }
  __syncthreads();
  if (t < 128) {
    float dd = 0.f;
    const float* w2r = mw2 + t * 16;
    for (int r = 0; r < 16; ++r) dd += hsum[r] * w2r[r];
    sc[b * 256 + 128 + t] = sigmoidf_(dd);
  }
}

// ---- 3. aggregate bank weights with k_att AND fold in_att into the weight ----
// agg[(b*256+o)*2304 + pq*256 + i] = (sum_k katt*ede) * in_att[b,i]
__global__ void k_agg(const float* __restrict__ ede, const float* __restrict__ katt,
                      const float* __restrict__ inatt, unsigned short* __restrict__ agg) {
  long long idx = (long long)blockIdx.x * 256 + threadIdx.x;  // 4,718,592 total
  int i = (int)((idx & 127) * 2);
  long long rest = idx >> 7;           // (b*256+o)*9+pq
  int pq = (int)(rest % 9);
  long long bo = rest / 9;
  int o = (int)(bo & 255);
  int b = (int)(bo >> 8);
  float k0 = katt[b * 4], k1 = katt[b * 4 + 1], k2 = katt[b * 4 + 2], k3 = katt[b * 4 + 3];
  const long long S = 256LL * 256 * 9;
  long long base = ((long long)o * 256 + i) * 9 + pq;
  float v0 = k0 * ede[base] + k1 * ede[base + S] + k2 * ede[base + 2 * S] + k3 * ede[base + 3 * S];
  float v1 = k0 * ede[base + 9] + k1 * ede[base + S + 9] + k2 * ede[base + 2 * S + 9] + k3 * ede[base + 3 * S + 9];
  v0 *= inatt[b * 256 + i];
  v1 *= inatt[b * 256 + i + 1];
  unsigned int u = (unsigned int)f2bf(v0) | ((unsigned int)f2bf(v1) << 16);
  *reinterpret_cast<unsigned int*>(agg + ((bo * 9 + pq) << 8) + i) = u;
}

// ---- 4. phase-split deep-pipelined implicit-GEMM conv + fused epilogue/BN sums ----
// BM=256, BN=256 px, BK=32, 512 thr / 8 waves (2M x 4N), 4 LDS buffers, depth-3 pipeline.
// 2 phases per K-tile; per-K-tile counted vmcnt placed BEFORE the final barrier
// (wait-then-barrier publication: the barrier certifies all waves' STAGE(kt+1) landed).
__global__ __launch_bounds__(512, 2) void k_conv(
    const unsigned short* __restrict__ agg, const unsigned short* __restrict__ xtr,
    const float* __restrict__ oatt, const float* __restrict__ sc,
    const float* __restrict__ zerob, float* __restrict__ sums,
    float* __restrict__ zout) {
  __shared__ __align__(16) char smem[131072];
  int wg = blockIdx.x;
  int bswz = ((wg & 7) << 5) | (wg >> 3);  // chunked XCD swizzle: 2 batches/XCD
  int b = bswz >> 4, pt = bswz & 15;
  int tid = threadIdx.x;
  int l = tid & 63;
  int wv = tid >> 6;
  int wm = wv >> 2, wn = wv & 3;

  // staging geometry
  int r0 = tid >> 2, s0 = tid & 3;
  int r1 = r0 + 128;
  int f0 = (s0 ^ ((r0 >> 1) & 3)) << 3;
  int f1 = (s0 ^ ((r1 >> 1) & 3)) << 3;
  const unsigned short* aS0 = agg + (size_t)(b * 256 + r0) * 2304 + f0;
  const unsigned short* aS1 = agg + (size_t)(b * 256 + r1) * 2304 + f1;
  int p0 = pt * 256 + r0, p1 = pt * 256 + r1;
  int h0 = p0 >> 6, w0 = p0 & 63;
  int h1 = p1 >> 6, w1 = p1 & 63;
  const unsigned short* bS0 = xtr + (((size_t)b * 4096 + p0) << 8) + f0;
  const unsigned short* bS1 = xtr + (((size_t)b * 4096 + p1) << 8) + f1;
  const unsigned short* zb = (const unsigned short*)zerob;
  char* aD0 = smem + tid * 16;
  char* aD1 = smem + tid * 16 + 8192;
  char* bD0 = smem + 16384 + tid * 16;
  char* bD1 = smem + 16384 + tid * 16 + 8192;

  // fragment read offsets (swizzled)
  int aOff[8], bOff[4];
#pragma unroll
  for (int fm = 0; fm < 8; ++fm) {
    int R = wm * 128 + fm * 16 + (l & 15);
    aOff[fm] = R * 64 + (((l >> 4) ^ ((R >> 1) & 3)) << 4);
  }
#pragma unroll
  for (int fn = 0; fn < 4; ++fn) {
    int P = wn * 64 + fn * 16 + (l & 15);
    bOff[fn] = 16384 + P * 64 + (((l >> 4) ^ ((P >> 1) & 3)) << 4);
  }

  f32x4 acc[8][4];
  f32x4 zero4 = {0.f, 0.f, 0.f, 0.f};
#pragma unroll
  for (int i2 = 0; i2 < 8; ++i2)
#pragma unroll
    for (int j2 = 0; j2 < 4; ++j2) acc[i2][j2] = zero4;

  auto STAGE_A = [&](int k) {
    int bsel = (k & 3) << 15;
    glds16(aS0 + k * 32, aD0 + bsel);
    glds16(aS1 + k * 32, aD1 + bsel);
  };
  auto STAGE_B = [&](int k) {
    int bsel = (k & 3) << 15;
    int pq = k >> 3, cs = k & 7;
    int dp = (pq * 11) >> 5;
    int dq = pq - 3 * dp;
    int boff = ((dp - 1) * 64 + (dq - 1)) * 256 + cs * 32;
    int hh0 = h0 + dp - 1, ww0 = w0 + dq - 1;
    int hh1 = h1 + dp - 1, ww1 = w1 + dq - 1;
    bool ok0 = ((unsigned)hh0 < 64u) && ((unsigned)ww0 < 64u);
    bool ok1 = ((unsigned)hh1 < 64u) && ((unsigned)ww1 < 64u);
    glds16(ok0 ? (bS0 + boff) : zb, bD0 + bsel);
    glds16(ok1 ? (bS1 + boff) : zb, bD1 + bsel);
  };

// Two phases per K-tile. VMWAIT_STMT executes BEFORE the final barrier so the
// barrier publishes load-retirement across all waves (race fix vs round 4).
#define CONV_ITER(KT, DOSTAGE, VMWAIT_STMT)                                          \
  {                                                                                  \
    const char* base_ = smem + (((KT) & 3) << 15);                                   \
    bf16x8 af_[4], bv_[4];                                                           \
    _Pragma("unroll")                                                                \
    for (int f_ = 0; f_ < 4; ++f_) {                                                 \
      af_[f_] = *reinterpret_cast<const bf16x8*>(base_ + aOff[f_]);                  \
      bv_[f_] = *reinterpret_cast<const bf16x8*>(base_ + bOff[f_]);                  \
    }                                                                                \
    if (DOSTAGE) STAGE_A((KT) + 3);                                                  \
    __builtin_amdgcn_s_barrier();                                                    \
    asm volatile("s_waitcnt lgkmcnt(0)" ::: "memory");                               \
    __builtin_amdgcn_sched_barrier(0);                                               \
    __builtin_amdgcn_s_setprio(1);                                                   \
    _Pragma("unroll")                                                                \
    for (int fm_ = 0; fm_ < 4; ++fm_)                                                \
      _Pragma("unroll")                                                              \
      for (int fn_ = 0; fn_ < 4; ++fn_)                                              \
        acc[fm_][fn_] = __builtin_amdgcn_mfma_f32_16x16x32_bf16(                     \
            af_[fm_], bv_[fn_], acc[fm_][fn_], 0, 0, 0);                             \
    __builtin_amdgcn_s_setprio(0);                                                   \
    __builtin_amdgcn_sched_barrier(0);                                               \
    __builtin_amdgcn_s_barrier();                                                    \
    bf16x8 ag_[4];                                                                   \
    _Pragma("unroll")                                                                \
    for (int f_ = 0; f_ < 4; ++f_)                                                   \
      ag_[f_] = *reinterpret_cast<const bf16x8*>(base_ + aOff[4 + f_]);              \
    if (DOSTAGE) STAGE_B((KT) + 3);                                                  \
    __builtin_amdgcn_s_barrier();                                                    \
    asm volatile("s_waitcnt lgkmcnt(0)" ::: "memory");                               \
    __builtin_amdgcn_sched_barrier(0);                                               \
    __builtin_amdgcn_s_setprio(1);                                                   \
    _Pragma("unroll")                                                                \
    for (int fm_ = 0; fm_ < 4; ++fm_)                                                \
      _Pragma("unroll")                                                              \
      for (int fn_ = 0; fn_ < 4; ++fn_)                                              \
        acc[4 + fm_][fn_] = __builtin_amdgcn_mfma_f32_16x16x32_bf16(                 \
            ag_[fm_], bv_[fn_], acc[4 + fm_][fn_], 0, 0, 0);                         \
    __builtin_amdgcn_s_setprio(0);                                                   \
    __builtin_amdgcn_sched_barrier(0);                                               \
    VMWAIT_STMT;                                                                     \
    __builtin_amdgcn_s_barrier();                                                    \
  }

  // prologue: 3 K-tiles in flight (12 loads); publish buf0 (wait-then-barrier)
  STAGE_A(0); STAGE_B(0); STAGE_A(1); STAGE_B(1); STAGE_A(2); STAGE_B(2);
  asm volatile("s_waitcnt vmcnt(8)" ::: "memory");
  __builtin_amdgcn_s_barrier();
  // main loop: 72 K-tiles (9 taps x 8 ch-steps)
  for (int kt = 0; kt < 69; ++kt) {
    CONV_ITER(kt, true, asm volatile("s_waitcnt vmcnt(8)" ::: "memory"));
  }
  CONV_ITER(69, false, asm volatile("s_waitcnt vmcnt(4)" ::: "memory"));
  CONV_ITER(70, false, asm volatile("s_waitcnt vmcnt(0)" ::: "memory"));
  CONV_ITER(71, false, (void)0);
#undef CONV_ITER
  __syncthreads();

  // ---- epilogue: z = Q*out_att + bf16(x)[oc]*sc[oc]; fused BN partial sums ----
  float* ls = (float*)smem;  // [256] sum, [256] sumsq
  ls[tid] = 0.f;
  __syncthreads();

#pragma unroll
  for (int fm = 0; fm < 8; ++fm) {
#pragma unroll
    for (int r = 0; r < 4; ++r) {
      int m = wm * 128 + fm * 16 + ((l >> 4) << 2) + r;
      int oc = ((m & 3) << 6) | (m >> 2);
      float oav = oatt[b * 256 + m];
      float scv = sc[b * 256 + oc];
      const unsigned short* xrow = xtr + (((size_t)b * 4096 + pt * 256) << 8) + oc;
      float* zrow = zout + (((size_t)b * 256 + m) << 12) + pt * 256;
      float psum = 0.f, psum2 = 0.f;
#pragma unroll
      for (int fn = 0; fn < 4; ++fn) {
        int n = wn * 64 + fn * 16 + (l & 15);
        float zv = acc[fm][fn][r] * oav + bf2f(xrow[(size_t)n << 8]) * scv;
        zrow[n] = zv;
        psum += zv; psum2 += zv * zv;
      }
#pragma unroll
      for (int d = 8; d > 0; d >>= 1) {
        psum += __shfl_down(psum, d, 16);
        psum2 += __shfl_down(psum2, d, 16);
      }
      if ((l & 15) == 0) {
        atomicAdd(&ls[m], psum);
        atomicAdd(&ls[256 + m], psum2);
      }
    }
  }
  __syncthreads();
  if (tid < 256) {
    atomicAdd(&sums[tid], ls[tid]);
    atomicAdd(&sums[256 + tid], ls[256 + tid]);
  }
}

// ---- 5. BN finalize + apply + ReLU (in place on d_out) ----
__global__ void k_apply(float* __restrict__ z, const float* __restrict__ sums,
                        const float* __restrict__ gamma, const float* __restrict__ beta) {
  int idx = blockIdx.x * 256 + threadIdx.x;
  for (int i = idx; i < 4194304; i += 4096 * 256) {
    int c = (i >> 10) & 255;
    float mean = sums[c] * (1.f / 65536.f);
    float var = sums[256 + c] * (1.f / 65536.f) - mean * mean;
    float scale = gamma[c] * rsqrtf(var + 1e-5f);
    float shift = beta[c] - mean * scale;
    float4* p = reinterpret_cast<float4*>(z) + i;
    float4 v = *p;
    v.x = fmaxf(v.x * scale + shift, 0.f);
    v.y = fmaxf(v.y * scale + shift, 0.f);
    v.z = fmaxf(v.z * scale + shift, 0.f);
    v.w = fmaxf(v.w * scale + shift, 0.f);
    *p = v;
  }
}

extern "C" void kernel_launch(void* const* d_in, const int* in_sizes, int n_in,
                              void* d_out, int out_size, void* d_ws, size_t ws_size,
                              hipStream_t stream) {
  (void)in_sizes; (void)n_in; (void)out_size; (void)ws_size;
  const float* x = (const float*)d_in[0];
  const float* aw3 = (const float*)d_in[1];
  const float* Wout = (const float*)d_in[2];
  const float* Wk = (const float*)d_in[3];
  const float* ede = (const float*)d_in[4];
  const float* lw3 = (const float*)d_in[5];
  const float* lbia = (const float*)d_in[6];
  const float* mw1 = (const float*)d_in[7];
  const float* mw2 = (const float*)d_in[8];
  const float* gamma = (const float*)d_in[9];
  const float* beta = (const float*)d_in[10];

  char* ws = (char*)d_ws;
  float* inatt = (float*)(ws + 32768);
  float* oatt  = (float*)(ws + 49152);
  float* katt  = (float*)(ws + 65536);
  float* sc    = (float*)(ws + 65792);
  float* zerob = (float*)(ws + 82176);
  float* sums  = (float*)(ws + 82432);
  unsigned short* xtr = (unsigned short*)(ws + 262144);                // 32MB
  unsigned short* agg = (unsigned short*)(ws + 262144 + 33554432);     // 18.9MB
  // psum/pmax alias the agg region (consumed by k_tiny before k_agg writes agg)
  float* psum = (float*)(ws + 262144 + 33554432);                      // 1MB
  float* pmax = (float*)(ws + 262144 + 33554432 + 1048576);            // 1MB
  float* z = (float*)d_out;

  k_pre<<<dim3(64, 4, 16), 256, 0, stream>>>(x, xtr, psum, pmax);
  k_tiny<<<16, 256, 0, stream>>>(psum, pmax, aw3, Wout, Wk, lw3, lbia, mw1, mw2,
                                 inatt, oatt, katt, sc, sums, zerob);
  k_agg<<<18432, 256, 0, stream>>>(ede, katt, inatt, agg);
  k_conv<<<256, 512, 0, stream>>>(agg, xtr, oatt, sc, zerob, sums, z);
  k_apply<<<4096, 256, 0, stream>>>(z, sums, gamma, beta);
}

// Round 6
// 231.927 us; speedup vs baseline: 1.1005x; 1.1005x over previous
//
#include <hip/hip_runtime.h>
#include <hip/hip_bf16.h>
#include <stdint.h>

#define HW_ 4096

typedef float f32x4 __attribute__((ext_vector_type(4)));
typedef short bf16x8 __attribute__((ext_vector_type(8)));

__device__ __forceinline__ unsigned short f2bf(float f) {
  __hip_bfloat16 h = __float2bfloat16(f);
  return *reinterpret_cast<unsigned short*>(&h);
}
__device__ __forceinline__ float sigmoidf_(float x) { return 1.f / (1.f + __expf(-x)); }

__device__ __forceinline__ void glds16(const void* g, void* l) {
  __builtin_amdgcn_global_load_lds(
      (const __attribute__((address_space(1))) unsigned int*)g,
      (__attribute__((address_space(3))) unsigned int*)l, 16, 0, 0);
}

// ---- 1. single pass over x (float4 loads): per-(b,c) partial mean/max + bf16
//         transpose to xtr[b][hw][c] ----
__global__ void k_pre(const float* __restrict__ x, unsigned short* __restrict__ xtr,
                      float* __restrict__ psum, float* __restrict__ pmax) {
  int hwb = blockIdx.x;  // 64 hw per block
  int cb = blockIdx.y;   // 64 c per block
  int b = blockIdx.z;
  int t = threadIdx.x;
  __shared__ float sv[64][65];
  int h16 = t & 15, g = t >> 4;
#pragma unroll
  for (int i = 0; i < 4; ++i) {
    int c_l = g + i * 16;
    float4 v = *reinterpret_cast<const float4*>(
        x + (((size_t)b * 256 + cb * 64 + c_l) << 12) + hwb * 64 + h16 * 4);
    *reinterpret_cast<float4*>(&sv[c_l][h16 * 4]) = v;
  }
  __syncthreads();
  // per-channel partials: 4 threads per channel, 16 hw each, 2-step shuffle
  {
    int c_l = t >> 2, q = t & 3;
    float s16 = 0.f, m16 = -3.4e38f;
#pragma unroll
    for (int j = 0; j < 16; ++j) {
      float vv = sv[c_l][q * 16 + j];
      s16 += vv; m16 = fmaxf(m16, vv);
    }
    s16 += __shfl_xor(s16, 1); s16 += __shfl_xor(s16, 2);
    m16 = fmaxf(m16, __shfl_xor(m16, 1)); m16 = fmaxf(m16, __shfl_xor(m16, 2));
    if (q == 0) {
      int c = cb * 64 + c_l;
      psum[(((size_t)b * 256 + c) << 6) + hwb] = s16;
      pmax[(((size_t)b * 256 + c) << 6) + hwb] = m16;
    }
  }
  // transpose to xtr (bf16, pixel-major)
#pragma unroll
  for (int i = 0; i < 8; ++i) {
    int fp = t + i * 256;
    int hw2 = fp >> 5;
    int cp = (fp & 31) * 2;
    unsigned int u = (unsigned int)f2bf(sv[cp][hw2]) | ((unsigned int)f2bf(sv[cp + 1][hw2]) << 16);
    *reinterpret_cast<unsigned int*>(xtr + (((size_t)b * 4096 + hwb * 64 + hw2) << 8) + cb * 64 + cp) = u;
  }
}

// ---- 2. small per-batch math (+ zero BN accumulators + zero page) ----
__global__ void k_tiny(const float* __restrict__ psum, const float* __restrict__ pmax,
                       const float* __restrict__ aw3, const float* __restrict__ Wout,
                       const float* __restrict__ Wk, const float* __restrict__ lw3,
                       const float* __restrict__ lbia, const float* __restrict__ mw1,
                       const float* __restrict__ mw2,
                       float* __restrict__ in_att, float* __restrict__ out_att,
                       float* __restrict__ katt, float* __restrict__ sc,
                       float* __restrict__ sums, float* __restrict__ zerob) {
  int b = blockIdx.x, t = threadIdx.x;
  __shared__ float g[256], tt[256], red[256], hsum[16], ksm[4], mx[128];
  {
    const float* pp = psum + ((size_t)(b * 256 + t) << 6);
    const float* pm = pmax + ((size_t)(b * 256 + t) << 6);
    float s = 0.f, m = -3.4e38f;
    for (int j = 0; j < 64; ++j) { s += pp[j]; m = fmaxf(m, pm[j]); }
    g[t] = s * (1.f / 4096.f);
    if (t >= 128) mx[t - 128] = m;
  }
  if (b == 0) {
    sums[t] = 0.f; sums[256 + t] = 0.f;
    if (t < 16) zerob[t] = 0.f;
  }
  __syncthreads();
  float c0 = aw3[0], c1 = aw3[1], c2 = aw3[2];
  float tv = c1 * g[t];
  if (t > 0) tv += c0 * g[t - 1];
  if (t < 255) tv += c2 * g[t + 1];
  tt[t] = tv;
  in_att[b * 256 + t] = sigmoidf_(tv);
  __syncthreads();
  {
    float d = 0.f;
    const float* wr = Wout + (size_t)t * 256;
    for (int c = 0; c < 256; ++c) d += tt[c] * wr[c];
    out_att[b * 256 + t] = sigmoidf_(d);
  }
  int k = t >> 6, lane = t & 63;
  {
    float pk = 0.f;
    for (int c = lane; c < 256; c += 64) pk += tt[c] * Wk[k * 256 + c];
    red[t] = pk; __syncthreads();
    for (int off = 32; off > 0; off >>= 1) {
      if (lane < off) red[t] += red[t + off];
      __syncthreads();
    }
    if (t == 0) {
      float l0 = red[0], l1 = red[64], l2 = red[128], l3 = red[192];
      float mm = fmaxf(fmaxf(l0, l1), fmaxf(l2, l3));
      float e0 = __expf(l0 - mm), e1 = __expf(l1 - mm), e2 = __expf(l2 - mm), e3 = __expf(l3 - mm);
      float inv = 1.f / (e0 + e1 + e2 + e3);
      ksm[0] = e0 * inv; ksm[1] = e1 * inv; ksm[2] = e2 * inv; ksm[3] = e3 * inv;
    }
    __syncthreads();
    if (t < 4) katt[b * 4 + t] = ksm[t];
  }
  if (t < 128) {
    float a0 = lw3[0], a1 = lw3[1], a2 = lw3[2];
    float sv = a1 * g[t] + lbia[0];
    if (t > 0) sv += a0 * g[t - 1];
    if (t < 127) sv += a2 * g[t + 1];
    sc[b * 256 + t] = sigmoidf_(sv);
  }
  __syncthreads();
  if (t < 16) {
    float d1 = 0.f, d2 = 0.f;
    const float* w1r = mw1 + t * 128;
    for (int j = 0; j < 128; ++j) { d1 += mx[j] * w1r[j]; d2 += g[128 + j] * w1r[j]; }
    hsum[t] = fmaxf(d1, 0.f) + fmaxf(d2, 0.f);
  }
  __syncthreads();
  if (t < 128) {
    float dd = 0.f;
    const float* w2r = mw2 + t * 16;
    for (int r = 0; r < 16; ++r) dd += hsum[r] * w2r[r];
    sc[b * 256 + 128 + t] = sigmoidf_(dd);
  }
}

// ---- 3. aggregate bank weights with k_att AND fold in_att into the weight ----
// agg[(b*256+o)*2304 + pq*256 + i] = (sum_k katt*ede) * in_att[b,i]
__global__ void k_agg(const float* __restrict__ ede, const float* __restrict__ katt,
                      const float* __restrict__ inatt, unsigned short* __restrict__ agg) {
  long long idx = (long long)blockIdx.x * 256 + threadIdx.x;  // 4,718,592 total
  int i = (int)((idx & 127) * 2);
  long long rest = idx >> 7;           // (b*256+o)*9+pq
  int pq = (int)(rest % 9);
  long long bo = rest / 9;
  int o = (int)(bo & 255);
  int b = (int)(bo >> 8);
  float k0 = katt[b * 4], k1 = katt[b * 4 + 1], k2 = katt[b * 4 + 2], k3 = katt[b * 4 + 3];
  const long long S = 256LL * 256 * 9;
  long long base = ((long long)o * 256 + i) * 9 + pq;
  float v0 = k0 * ede[base] + k1 * ede[base + S] + k2 * ede[base + 2 * S] + k3 * ede[base + 3 * S];
  float v1 = k0 * ede[base + 9] + k1 * ede[base + S + 9] + k2 * ede[base + 2 * S + 9] + k3 * ede[base + 3 * S + 9];
  v0 *= inatt[b * 256 + i];
  v1 *= inatt[b * 256 + i + 1];
  unsigned int u = (unsigned int)f2bf(v0) | ((unsigned int)f2bf(v1) << 16);
  *reinterpret_cast<unsigned int*>(agg + ((bo * 9 + pq) << 8) + i) = u;
}

// ---- 4. deep-pipelined implicit-GEMM conv (round-3 proven loop), fused epilogue/BN ----
// BM=256, BN=256 px, BK=32, 512 thr / 8 waves (2M x 4N), 4 LDS buffers, depth-3,
// one barrier + one counted vmcnt(8) per K-tile (publication via next iter's barrier).
__global__ __launch_bounds__(512, 2) void k_conv(
    const unsigned short* __restrict__ agg, const unsigned short* __restrict__ xtr,
    const float* __restrict__ x, const float* __restrict__ oatt,
    const float* __restrict__ sc, const float* __restrict__ zerob,
    float* __restrict__ sums, float* __restrict__ zout) {
  __shared__ __align__(16) char smem[131072];
  int wg = blockIdx.x;
  int bswz = ((wg & 7) << 5) | (wg >> 3);  // chunked XCD swizzle: 2 batches/XCD
  int b = bswz >> 4, pt = bswz & 15;
  int tid = threadIdx.x;
  int l = tid & 63;
  int wv = tid >> 6;
  int wm = wv >> 2, wn = wv & 3;

  // staging geometry
  int r0 = tid >> 2, s0 = tid & 3;
  int r1 = r0 + 128;
  int f0 = (s0 ^ ((r0 >> 1) & 3)) << 3;
  int f1 = (s0 ^ ((r1 >> 1) & 3)) << 3;
  const unsigned short* aS0 = agg + (size_t)(b * 256 + r0) * 2304 + f0;
  const unsigned short* aS1 = agg + (size_t)(b * 256 + r1) * 2304 + f1;
  int p0 = pt * 256 + r0, p1 = pt * 256 + r1;
  int h0 = p0 >> 6, w0 = p0 & 63;
  int h1 = p1 >> 6, w1 = p1 & 63;
  const unsigned short* bS0 = xtr + (((size_t)b * 4096 + p0) << 8) + f0;
  const unsigned short* bS1 = xtr + (((size_t)b * 4096 + p1) << 8) + f1;
  const unsigned short* zb = (const unsigned short*)zerob;
  char* aD0 = smem + tid * 16;
  char* aD1 = smem + tid * 16 + 8192;
  char* bD0 = smem + 16384 + tid * 16;
  char* bD1 = smem + 16384 + tid * 16 + 8192;

  // fragment read offsets (swizzled)
  int aOff[8], bOff[4];
#pragma unroll
  for (int fm = 0; fm < 8; ++fm) {
    int R = wm * 128 + fm * 16 + (l & 15);
    aOff[fm] = R * 64 + (((l >> 4) ^ ((R >> 1) & 3)) << 4);
  }
#pragma unroll
  for (int fn = 0; fn < 4; ++fn) {
    int P = wn * 64 + fn * 16 + (l & 15);
    bOff[fn] = 16384 + P * 64 + (((l >> 4) ^ ((P >> 1) & 3)) << 4);
  }

  f32x4 acc[8][4];
  f32x4 zero4 = {0.f, 0.f, 0.f, 0.f};
#pragma unroll
  for (int i2 = 0; i2 < 8; ++i2)
#pragma unroll
    for (int j2 = 0; j2 < 4; ++j2) acc[i2][j2] = zero4;

  auto STAGE = [&](int k) {
    int bsel = (k & 3) << 15;
    int pq = k >> 3, cs = k & 7;
    int dp = (pq * 11) >> 5;             // pq/3
    int dq = pq - 3 * dp;
    glds16(aS0 + k * 32, aD0 + bsel);
    glds16(aS1 + k * 32, aD1 + bsel);
    int boff = ((dp - 1) * 64 + (dq - 1)) * 256 + cs * 32;
    int hh0 = h0 + dp - 1, ww0 = w0 + dq - 1;
    int hh1 = h1 + dp - 1, ww1 = w1 + dq - 1;
    bool ok0 = ((unsigned)hh0 < 64u) && ((unsigned)ww0 < 64u);
    bool ok1 = ((unsigned)hh1 < 64u) && ((unsigned)ww1 < 64u);
    glds16(ok0 ? (bS0 + boff) : zb, bD0 + bsel);
    glds16(ok1 ? (bS1 + boff) : zb, bD1 + bsel);
  };

  auto COMPUTE = [&](int k) {
    const char* base = smem + ((k & 3) << 15);
    bf16x8 af[8], bv[4];
#pragma unroll
    for (int f = 0; f < 4; ++f) {
      af[f] = *reinterpret_cast<const bf16x8*>(base + aOff[f]);
      bv[f] = *reinterpret_cast<const bf16x8*>(base + bOff[f]);
    }
#pragma unroll
    for (int f = 4; f < 8; ++f) af[f] = *reinterpret_cast<const bf16x8*>(base + aOff[f]);
    __builtin_amdgcn_s_setprio(1);
#pragma unroll
    for (int fm = 0; fm < 8; ++fm)
#pragma unroll
      for (int fn = 0; fn < 4; ++fn)
        acc[fm][fn] = __builtin_amdgcn_mfma_f32_16x16x32_bf16(af[fm], bv[fn], acc[fm][fn], 0, 0, 0);
    __builtin_amdgcn_s_setprio(0);
  };

  // prologue: 3 K-tiles in flight (12 loads)
  STAGE(0); STAGE(1); STAGE(2);
  asm volatile("s_waitcnt vmcnt(8)" ::: "memory");  // own KT0 landed
  // main loop: 72 K-tiles (9 taps x 8 ch-steps). Barrier-after-vmcnt across
  // iterations publishes KT(kt) to all waves before COMPUTE(kt) (round-3 proven).
  for (int kt = 0; kt < 69; ++kt) {
    __builtin_amdgcn_s_barrier();
    STAGE(kt + 3);
    asm volatile("s_waitcnt vmcnt(8)" ::: "memory"); // retire own KT(kt+1)
    COMPUTE(kt);
  }
  __builtin_amdgcn_s_barrier();
  asm volatile("s_waitcnt vmcnt(4)" ::: "memory");
  COMPUTE(69);
  __builtin_amdgcn_s_barrier();
  asm volatile("s_waitcnt vmcnt(0)" ::: "memory");
  COMPUTE(70);
  __builtin_amdgcn_s_barrier();
  COMPUTE(71);
  __syncthreads();

  // ---- epilogue: z = Q*out_att + x[oc]*sc[oc] (coalesced fp32 x); fused BN sums ----
  float* ls = (float*)smem;  // [256] sum, [256] sumsq
  ls[tid] = 0.f;
  __syncthreads();

#pragma unroll
  for (int fm = 0; fm < 8; ++fm) {
#pragma unroll
    for (int r = 0; r < 4; ++r) {
      int m = wm * 128 + fm * 16 + ((l >> 4) << 2) + r;
      int oc = ((m & 3) << 6) | (m >> 2);
      float oav = oatt[b * 256 + m];
      float scv = sc[b * 256 + oc];
      const float* xrow = x + (((size_t)b * 256 + oc) << 12) + pt * 256;
      float* zrow = zout + (((size_t)b * 256 + m) << 12) + pt * 256;
      float psum = 0.f, psum2 = 0.f;
#pragma unroll
      for (int fn = 0; fn < 4; ++fn) {
        int n = wn * 64 + fn * 16 + (l & 15);
        float zv = acc[fm][fn][r] * oav + xrow[n] * scv;
        zrow[n] = zv;
        psum += zv; psum2 += zv * zv;
      }
#pragma unroll
      for (int d = 8; d > 0; d >>= 1) {
        psum += __shfl_down(psum, d, 16);
        psum2 += __shfl_down(psum2, d, 16);
      }
      if ((l & 15) == 0) {
        atomicAdd(&ls[m], psum);
        atomicAdd(&ls[256 + m], psum2);
      }
    }
  }
  __syncthreads();
  if (tid < 256) {
    atomicAdd(&sums[tid], ls[tid]);
    atomicAdd(&sums[256 + tid], ls[256 + tid]);
  }
}

// ---- 5. BN finalize + apply + ReLU (in place on d_out) ----
__global__ void k_apply(float* __restrict__ z, const float* __restrict__ sums,
                        const float* __restrict__ gamma, const float* __restrict__ beta) {
  int idx = blockIdx.x * 256 + threadIdx.x;
  for (int i = idx; i < 4194304; i += 4096 * 256) {
    int c = (i >> 10) & 255;
    float mean = sums[c] * (1.f / 65536.f);
    float var = sums[256 + c] * (1.f / 65536.f) - mean * mean;
    float scale = gamma[c] * rsqrtf(var + 1e-5f);
    float shift = beta[c] - mean * scale;
    float4* p = reinterpret_cast<float4*>(z) + i;
    float4 v = *p;
    v.x = fmaxf(v.x * scale + shift, 0.f);
    v.y = fmaxf(v.y * scale + shift, 0.f);
    v.z = fmaxf(v.z * scale + shift, 0.f);
    v.w = fmaxf(v.w * scale + shift, 0.f);
    *p = v;
  }
}

extern "C" void kernel_launch(void* const* d_in, const int* in_sizes, int n_in,
                              void* d_out, int out_size, void* d_ws, size_t ws_size,
                              hipStream_t stream) {
  (void)in_sizes; (void)n_in; (void)out_size; (void)ws_size;
  const float* x = (const float*)d_in[0];
  const float* aw3 = (const float*)d_in[1];
  const float* Wout = (const float*)d_in[2];
  const float* Wk = (const float*)d_in[3];
  const float* ede = (const float*)d_in[4];
  const float* lw3 = (const float*)d_in[5];
  const float* lbia = (const float*)d_in[6];
  const float* mw1 = (const float*)d_in[7];
  const float* mw2 = (const float*)d_in[8];
  const float* gamma = (const float*)d_in[9];
  const float* beta = (const float*)d_in[10];

  char* ws = (char*)d_ws;
  float* inatt = (float*)(ws + 32768);
  float* oatt  = (float*)(ws + 49152);
  float* katt  = (float*)(ws + 65536);
  float* sc    = (float*)(ws + 65792);
  float* zerob = (float*)(ws + 82176);
  float* sums  = (float*)(ws + 82432);
  unsigned short* xtr = (unsigned short*)(ws + 262144);                // 32MB
  unsigned short* agg = (unsigned short*)(ws + 262144 + 33554432);     // 18.9MB
  // psum/pmax alias the agg region (consumed by k_tiny before k_agg writes agg)
  float* psum = (float*)(ws + 262144 + 33554432);                      // 1MB
  float* pmax = (float*)(ws + 262144 + 33554432 + 1048576);            // 1MB
  float* z = (float*)d_out;

  k_pre<<<dim3(64, 4, 16), 256, 0, stream>>>(x, xtr, psum, pmax);
  k_tiny<<<16, 256, 0, stream>>>(psum, pmax, aw3, Wout, Wk, lw3, lbia, mw1, mw2,
                                 inatt, oatt, katt, sc, sums, zerob);
  k_agg<<<18432, 256, 0, stream>>>(ede, katt, inatt, agg);
  k_conv<<<256, 512, 0, stream>>>(agg, xtr, x, oatt, sc, zerob, sums, z);
  k_apply<<<4096, 256, 0, stream>>>(z, sums, gamma, beta);
}

// Round 7
// 148.808 us; speedup vs baseline: 1.7153x; 1.5586x over previous
//
#include <hip/hip_runtime.h>
#include <hip/hip_bf16.h>
#include <stdint.h>

#define HW_ 4096

typedef float f32x4 __attribute__((ext_vector_type(4)));
typedef short bf16x8 __attribute__((ext_vector_type(8)));

__device__ __forceinline__ unsigned short f2bf(float f) {
  __hip_bfloat16 h = __float2bfloat16(f);
  return *reinterpret_cast<unsigned short*>(&h);
}
__device__ __forceinline__ float sigmoidf_(float x) { return 1.f / (1.f + __expf(-x)); }

__device__ __forceinline__ void glds16(const void* g, void* l) {
  __builtin_amdgcn_global_load_lds(
      (const __attribute__((address_space(1))) unsigned int*)g,
      (__attribute__((address_space(3))) unsigned int*)l, 16, 0, 0);
}

// ---- 1. single pass over x (float4 loads): per-(b,c) partial mean/max + bf16
//         transpose to xtr[b][hw][c] (16B stores) ----
__global__ void k_pre(const float* __restrict__ x, unsigned short* __restrict__ xtr,
                      float* __restrict__ psum, float* __restrict__ pmax) {
  int hwb = blockIdx.x;  // 64 hw per block
  int cb = blockIdx.y;   // 64 c per block
  int b = blockIdx.z;
  int t = threadIdx.x;
  __shared__ float sv[64][65];
  int h16 = t & 15, g = t >> 4;
#pragma unroll
  for (int i = 0; i < 4; ++i) {
    int c_l = g + i * 16;
    float4 v = *reinterpret_cast<const float4*>(
        x + (((size_t)b * 256 + cb * 64 + c_l) << 12) + hwb * 64 + h16 * 4);
    *reinterpret_cast<float4*>(&sv[c_l][h16 * 4]) = v;
  }
  __syncthreads();
  {
    int c_l = t >> 2, q = t & 3;
    float s16 = 0.f, m16 = -3.4e38f;
#pragma unroll
    for (int j = 0; j < 16; ++j) {
      float vv = sv[c_l][q * 16 + j];
      s16 += vv; m16 = fmaxf(m16, vv);
    }
    s16 += __shfl_xor(s16, 1); s16 += __shfl_xor(s16, 2);
    m16 = fmaxf(m16, __shfl_xor(m16, 1)); m16 = fmaxf(m16, __shfl_xor(m16, 2));
    if (q == 0) {
      int c = cb * 64 + c_l;
      psum[(((size_t)b * 256 + c) << 6) + hwb] = s16;
      pmax[(((size_t)b * 256 + c) << 6) + hwb] = m16;
    }
  }
  // transpose to xtr (bf16, pixel-major), 16B per store
#pragma unroll
  for (int i = 0; i < 2; ++i) {
    int fp = t + i * 256;
    int hw2 = fp >> 3;        // 0..63
    int cp = (fp & 7) * 8;    // 0..56
    uint4 uu;
    uu.x = (unsigned)f2bf(sv[cp + 0][hw2]) | ((unsigned)f2bf(sv[cp + 1][hw2]) << 16);
    uu.y = (unsigned)f2bf(sv[cp + 2][hw2]) | ((unsigned)f2bf(sv[cp + 3][hw2]) << 16);
    uu.z = (unsigned)f2bf(sv[cp + 4][hw2]) | ((unsigned)f2bf(sv[cp + 5][hw2]) << 16);
    uu.w = (unsigned)f2bf(sv[cp + 6][hw2]) | ((unsigned)f2bf(sv[cp + 7][hw2]) << 16);
    *reinterpret_cast<uint4*>(xtr + (((size_t)b * 4096 + hwb * 64 + hw2) << 8) + cb * 64 + cp) = uu;
  }
}

// ---- 2. small per-batch math (vectorized; + zero BN accumulators + zero page) ----
__global__ void k_tiny(const float* __restrict__ psum, const float* __restrict__ pmax,
                       const float* __restrict__ aw3, const float* __restrict__ Wout,
                       const float* __restrict__ Wk, const float* __restrict__ lw3,
                       const float* __restrict__ lbia, const float* __restrict__ mw1,
                       const float* __restrict__ mw2,
                       float* __restrict__ in_att, float* __restrict__ out_att,
                       float* __restrict__ katt, float* __restrict__ sc,
                       float* __restrict__ sums, float* __restrict__ zerop) {
  int b = blockIdx.x, t = threadIdx.x;
  __shared__ float g[256], tt[256], red[256], hsum[16], ksm[4], mx[128];
  {
    const float4* pp = reinterpret_cast<const float4*>(psum + ((size_t)(b * 256 + t) << 6));
    const float4* pm = reinterpret_cast<const float4*>(pmax + ((size_t)(b * 256 + t) << 6));
    float s = 0.f, m = -3.4e38f;
#pragma unroll
    for (int j = 0; j < 16; ++j) {
      float4 a = pp[j]; s += (a.x + a.y) + (a.z + a.w);
      float4 q4 = pm[j];
      m = fmaxf(m, fmaxf(fmaxf(q4.x, q4.y), fmaxf(q4.z, q4.w)));
    }
    g[t] = s * (1.f / 4096.f);
    if (t >= 128) mx[t - 128] = m;
  }
  if (b == 0) {
    sums[t] = 0.f; sums[256 + t] = 0.f;
    zerop[t] = 0.f;
  }
  __syncthreads();
  float c0 = aw3[0], c1 = aw3[1], c2 = aw3[2];
  float tv = c1 * g[t];
  if (t > 0) tv += c0 * g[t - 1];
  if (t < 255) tv += c2 * g[t + 1];
  tt[t] = tv;
  in_att[b * 256 + t] = sigmoidf_(tv);
  __syncthreads();
  {
    float d = 0.f;
    const float4* wr = reinterpret_cast<const float4*>(Wout + (size_t)t * 256);
    for (int c4 = 0; c4 < 64; ++c4) {
      float4 wv4 = wr[c4];
      d += tt[c4 * 4] * wv4.x + tt[c4 * 4 + 1] * wv4.y + tt[c4 * 4 + 2] * wv4.z + tt[c4 * 4 + 3] * wv4.w;
    }
    out_att[b * 256 + t] = sigmoidf_(d);
  }
  int k = t >> 6, lane = t & 63;
  {
    float pk = 0.f;
    for (int c = lane; c < 256; c += 64) pk += tt[c] * Wk[k * 256 + c];
    red[t] = pk; __syncthreads();
    for (int off = 32; off > 0; off >>= 1) {
      if (lane < off) red[t] += red[t + off];
      __syncthreads();
    }
    if (t == 0) {
      float l0 = red[0], l1 = red[64], l2 = red[128], l3 = red[192];
      float mm = fmaxf(fmaxf(l0, l1), fmaxf(l2, l3));
      float e0 = __expf(l0 - mm), e1 = __expf(l1 - mm), e2 = __expf(l2 - mm), e3 = __expf(l3 - mm);
      float inv = 1.f / (e0 + e1 + e2 + e3);
      ksm[0] = e0 * inv; ksm[1] = e1 * inv; ksm[2] = e2 * inv; ksm[3] = e3 * inv;
    }
    __syncthreads();
    if (t < 4) katt[b * 4 + t] = ksm[t];
  }
  if (t < 128) {
    float a0 = lw3[0], a1 = lw3[1], a2 = lw3[2];
    float sv = a1 * g[t] + lbia[0];
    if (t > 0) sv += a0 * g[t - 1];
    if (t < 127) sv += a2 * g[t + 1];
    sc[b * 256 + t] = sigmoidf_(sv);
  }
  __syncthreads();
  if (t < 16) {
    float d1 = 0.f, d2 = 0.f;
    const float* w1r = mw1 + t * 128;
    for (int j = 0; j < 128; ++j) { d1 += mx[j] * w1r[j]; d2 += g[128 + j] * w1r[j]; }
    hsum[t] = fmaxf(d1, 0.f) + fmaxf(d2, 0.f);
  }
  __syncthreads();
  if (t < 128) {
    float dd = 0.f;
    const float* w2r = mw2 + t * 16;
    for (int r = 0; r < 16; ++r) dd += hsum[r] * w2r[r];
    sc[b * 256 + 128 + t] = sigmoidf_(dd);
  }
}

// ---- 3. aggregate bank weights: LDS-tile ede per output channel o, apply all 16 b ----
// agg[(b*256+o)*2304 + pq*256 + i] = (sum_k katt[b,k]*ede[k,o,i,pq]) * in_att[b,i]
__global__ __launch_bounds__(256) void k_agg(const float* __restrict__ ede,
                                             const float* __restrict__ katt,
                                             const float* __restrict__ inatt,
                                             unsigned short* __restrict__ agg) {
  __shared__ float eds[4][2304];
  int o = blockIdx.x, t = threadIdx.x;
#pragma unroll
  for (int k = 0; k < 4; ++k) {
    const float* src = ede + ((size_t)k * 256 + o) * 2304;
#pragma unroll
    for (int j = 0; j < 9; ++j) eds[k][j * 256 + t] = src[j * 256 + t];
  }
  __syncthreads();
  int ii = (t & 127) * 2;
  int bh = t >> 7;
  for (int b2 = 0; b2 < 8; ++b2) {
    int b = b2 * 2 + bh;
    float k0 = katt[b * 4], k1 = katt[b * 4 + 1], k2 = katt[b * 4 + 2], k3 = katt[b * 4 + 3];
    float ia0 = inatt[b * 256 + ii], ia1 = inatt[b * 256 + ii + 1];
    size_t obase = ((size_t)(b * 256 + o) * 9) << 8;
#pragma unroll
    for (int pq = 0; pq < 9; ++pq) {
      float v0 = k0 * eds[0][ii * 9 + pq] + k1 * eds[1][ii * 9 + pq] +
                 k2 * eds[2][ii * 9 + pq] + k3 * eds[3][ii * 9 + pq];
      float v1 = k0 * eds[0][(ii + 1) * 9 + pq] + k1 * eds[1][(ii + 1) * 9 + pq] +
                 k2 * eds[2][(ii + 1) * 9 + pq] + k3 * eds[3][(ii + 1) * 9 + pq];
      v0 *= ia0; v1 *= ia1;
      unsigned int u = (unsigned)f2bf(v0) | ((unsigned)f2bf(v1) << 16);
      *reinterpret_cast<unsigned int*>(agg + obase + (pq << 8) + ii) = u;
    }
  }
}

// ---- 4. slab-reuse implicit-GEMM conv + fused epilogue/BN sums ----
// BM=256 (o), BN=256 px (4 image rows), 8 waves (2Mx4N). cs outer (8 x 32ch),
// pq inner (9 taps). B staged ONCE per cs as a 6-row x 64-px x 32-ch slab (24KB,
// double-buffered); taps = shifted LDS reads (clamped + edge-masked). A staged
// per (cs,pq) with depth-2 prefetch in 4 buffers. Round-3 publication discipline:
// each iter's vmcnt retires the loads needed by the NEXT compute; the next iter's
// top barrier publishes them. LDS = 4*16K (A) + 2*24K (slab) = 112 KB.
__global__ __launch_bounds__(512, 2) void k_conv(
    const unsigned short* __restrict__ agg, const unsigned short* __restrict__ xtr,
    const float* __restrict__ x, const float* __restrict__ oatt,
    const float* __restrict__ sc, const float* __restrict__ zerop,
    float* __restrict__ sums, float* __restrict__ zout) {
  __shared__ __align__(16) char smem[114688];
  int wg = blockIdx.x;
  int bswz = ((wg & 7) << 5) | (wg >> 3);  // 2 batches per XCD
  int b = bswz >> 4, pt = bswz & 15;
  int tid = threadIdx.x;
  int l = tid & 63;
  int wv = tid >> 6;
  int wm = wv >> 2, wn = wv & 3;          // wn = wave's image row (0..3)
  int w0 = l & 15, ks = l >> 4;
  bool maskl0 = (w0 == 0), maskl15 = (w0 == 15);

  // A staging geometry (2 x 16B per thread per A-tile), pre-swizzled source
  int r0 = tid >> 2, s0 = tid & 3;
  int r1 = r0 + 128;
  int f0 = (s0 ^ ((r0 >> 1) & 3)) << 3;
  int f1 = (s0 ^ ((r1 >> 1) & 3)) << 3;
  const unsigned short* aS0 = agg + (size_t)(b * 256 + r0) * 2304 + f0;
  const unsigned short* aS1 = agg + (size_t)(b * 256 + r1) * 2304 + f1;

  // slab staging sources (3 x 16B per thread per cs), pre-swizzled, border->zero
  auto slabsrc = [&](int j) -> const char* {
    int idx = j * 512 + tid;
    int P = idx >> 2, sp = idx & 3;
    int sr = P >> 6, w = P & 63;
    int imgrow = pt * 4 + sr - 1;
    int ir = imgrow < 0 ? 0 : (imgrow > 63 ? 63 : imgrow);
    int slog = sp ^ ((w >> 1) & 3);
    const char* gp = (const char*)(xtr + (((size_t)b * 4096 + ir * 64 + w) << 8) + slog * 8);
    return ((unsigned)imgrow < 64u) ? gp : (const char*)zerop;
  };
  const char* sb0_ = slabsrc(0);
  const char* sb1_ = slabsrc(1);
  const char* sb2_ = slabsrc(2);

  // A fragment read offsets (swizzled), within a 16KB A buffer
  int aOff[8];
#pragma unroll
  for (int fm = 0; fm < 8; ++fm) {
    int R = wm * 128 + fm * 16 + (l & 15);
    aOff[fm] = R * 64 + (((l >> 4) ^ ((R >> 1) & 3)) << 4);
  }

  f32x4 acc[8][4];
  f32x4 zero4 = {0.f, 0.f, 0.f, 0.f};
#pragma unroll
  for (int i2 = 0; i2 < 8; ++i2)
#pragma unroll
    for (int j2 = 0; j2 < 4; ++j2) acc[i2][j2] = zero4;

  bf16x8 z8 = {0, 0, 0, 0, 0, 0, 0, 0};

#define ASTG(COLELEMS, DSTIDX)                                           \
  { char* ad_ = smem + (DSTIDX) * 16384;                                 \
    glds16(aS0 + (COLELEMS), ad_ + tid * 16);                            \
    glds16(aS1 + (COLELEMS), ad_ + 8192 + tid * 16); }

#define SLSTG(CN)                                                        \
  { char* sd_ = smem + 65536 + (((CN) & 1) ? 24576 : 0);                 \
    glds16(sb0_ + (CN) * 64, sd_ + tid * 16);                            \
    glds16(sb1_ + (CN) * 64, sd_ + 8192 + tid * 16);                     \
    glds16(sb2_ + (CN) * 64, sd_ + 16384 + tid * 16); }

#define CITER(PQ, STG, VM)                                               \
  {                                                                      \
    __builtin_amdgcn_s_barrier();                                        \
    STG;                                                                 \
    asm volatile("s_waitcnt vmcnt(" VM ")" ::: "memory");                \
    const char* ab_ = smem + ((c + (PQ)) & 3) * 16384;                   \
    bf16x8 af_[8], bv_[4];                                               \
    _Pragma("unroll")                                                    \
    for (int f_ = 0; f_ < 8; ++f_)                                       \
      af_[f_] = *reinterpret_cast<const bf16x8*>(ab_ + aOff[f_]);        \
    const int dq_ = (PQ) % 3;                                            \
    const int rowb_ = (wn + (PQ) / 3) << 6;                              \
    _Pragma("unroll")                                                    \
    for (int fn_ = 0; fn_ < 4; ++fn_) {                                  \
      int wcol_ = w0 + fn_ * 16 + (dq_ - 1);                             \
      int wc_ = wcol_ < 0 ? 0 : (wcol_ > 63 ? 63 : wcol_);               \
      int bo_ = ((rowb_ + wc_) << 6) + ((ks ^ ((wc_ >> 1) & 3)) << 4);   \
      bv_[fn_] = *reinterpret_cast<const bf16x8*>(sb + bo_);             \
    }                                                                    \
    if (dq_ == 0) bv_[0] = maskl0 ? z8 : bv_[0];                         \
    if (dq_ == 2) bv_[3] = maskl15 ? z8 : bv_[3];                        \
    __builtin_amdgcn_s_setprio(1);                                       \
    _Pragma("unroll")                                                    \
    for (int fm_ = 0; fm_ < 8; ++fm_)                                    \
      _Pragma("unroll")                                                  \
      for (int fn_ = 0; fn_ < 4; ++fn_)                                  \
        acc[fm_][fn_] = __builtin_amdgcn_mfma_f32_16x16x32_bf16(         \
            af_[fm_], bv_[fn_], acc[fm_][fn_], 0, 0, 0);                 \
    __builtin_amdgcn_s_setprio(0);                                       \
  }

  // prologue: slab0 + A[0,0..2]; retire slab0+A00 (queue: 9 -> 4)
  SLSTG(0);
  ASTG(0, 0);
  ASTG(256, 1);
  ASTG(512, 2);
  asm volatile("s_waitcnt vmcnt(4)" ::: "memory");

  for (int c = 0; c < 7; ++c) {
    const char* sb = smem + 65536 + ((c & 1) ? 24576 : 0);
    CITER(0, { SLSTG(c + 1); ASTG(3 * 256 + c * 32, (c + 3) & 3); }, "7")
    CITER(1, ASTG(4 * 256 + c * 32, (c + 4) & 3), "7")
    CITER(2, ASTG(5 * 256 + c * 32, (c + 5) & 3), "4")
    CITER(3, ASTG(6 * 256 + c * 32, (c + 6) & 3), "4")
    CITER(4, ASTG(7 * 256 + c * 32, (c + 7) & 3), "4")
    CITER(5, ASTG(8 * 256 + c * 32, (c + 8) & 3), "4")
    CITER(6, ASTG(0 * 256 + (c + 1) * 32, (c + 9) & 3), "4")
    CITER(7, ASTG(1 * 256 + (c + 1) * 32, (c + 10) & 3), "4")
    CITER(8, ASTG(2 * 256 + (c + 1) * 32, (c + 11) & 3), "4")
  }
  {
    const int c = 7;
    const char* sb = smem + 65536 + 24576;
    CITER(0, ASTG(3 * 256 + 224, 2), "4")
    CITER(1, ASTG(4 * 256 + 224, 3), "4")
    CITER(2, ASTG(5 * 256 + 224, 0), "4")
    CITER(3, ASTG(6 * 256 + 224, 1), "4")
    CITER(4, ASTG(7 * 256 + 224, 2), "4")
    CITER(5, ASTG(8 * 256 + 224, 3), "4")
    CITER(6, {}, "2")
    CITER(7, {}, "0")
    CITER(8, {}, "0")
  }
#undef CITER
#undef ASTG
#undef SLSTG
  __syncthreads();

  // ---- epilogue: z = Q*out_att + x[oc]*sc[oc]; fused BN partial sums ----
  float* ls = (float*)smem;  // [256] sum, [256] sumsq
  ls[tid] = 0.f;
  __syncthreads();

#pragma unroll
  for (int fm = 0; fm < 8; ++fm) {
#pragma unroll
    for (int r = 0; r < 4; ++r) {
      int m = wm * 128 + fm * 16 + ((l >> 4) << 2) + r;
      int oc = ((m & 3) << 6) | (m >> 2);
      float oav = oatt[b * 256 + m];
      float scv = sc[b * 256 + oc];
      const float* xrow = x + (((size_t)b * 256 + oc) << 12) + pt * 256;
      float* zrow = zout + (((size_t)b * 256 + m) << 12) + pt * 256;
      float psv = 0.f, psv2 = 0.f;
#pragma unroll
      for (int fn = 0; fn < 4; ++fn) {
        int n = wn * 64 + fn * 16 + (l & 15);
        float zv = acc[fm][fn][r] * oav + xrow[n] * scv;
        zrow[n] = zv;
        psv += zv; psv2 += zv * zv;
      }
#pragma unroll
      for (int d = 8; d > 0; d >>= 1) {
        psv += __shfl_down(psv, d, 16);
        psv2 += __shfl_down(psv2, d, 16);
      }
      if ((l & 15) == 0) {
        atomicAdd(&ls[m], psv);
        atomicAdd(&ls[256 + m], psv2);
      }
    }
  }
  __syncthreads();
  if (tid < 256) {
    atomicAdd(&sums[tid], ls[tid]);
    atomicAdd(&sums[256 + tid], ls[256 + tid]);
  }
}

// ---- 5. BN finalize + apply + ReLU (in place on d_out) ----
__global__ void k_apply(float* __restrict__ z, const float* __restrict__ sums,
                        const float* __restrict__ gamma, const float* __restrict__ beta) {
  int idx = blockIdx.x * 256 + threadIdx.x;
  for (int i = idx; i < 4194304; i += 4096 * 256) {
    int c = (i >> 10) & 255;
    float mean = sums[c] * (1.f / 65536.f);
    float var = sums[256 + c] * (1.f / 65536.f) - mean * mean;
    float scale = gamma[c] * rsqrtf(var + 1e-5f);
    float shift = beta[c] - mean * scale;
    float4* p = reinterpret_cast<float4*>(z) + i;
    float4 v = *p;
    v.x = fmaxf(v.x * scale + shift, 0.f);
    v.y = fmaxf(v.y * scale + shift, 0.f);
    v.z = fmaxf(v.z * scale + shift, 0.f);
    v.w = fmaxf(v.w * scale + shift, 0.f);
    *p = v;
  }
}

extern "C" void kernel_launch(void* const* d_in, const int* in_sizes, int n_in,
                              void* d_out, int out_size, void* d_ws, size_t ws_size,
                              hipStream_t stream) {
  (void)in_sizes; (void)n_in; (void)out_size; (void)ws_size;
  const float* x = (const float*)d_in[0];
  const float* aw3 = (const float*)d_in[1];
  const float* Wout = (const float*)d_in[2];
  const float* Wk = (const float*)d_in[3];
  const float* ede = (const float*)d_in[4];
  const float* lw3 = (const float*)d_in[5];
  const float* lbia = (const float*)d_in[6];
  const float* mw1 = (const float*)d_in[7];
  const float* mw2 = (const float*)d_in[8];
  const float* gamma = (const float*)d_in[9];
  const float* beta = (const float*)d_in[10];

  char* ws = (char*)d_ws;
  float* inatt = (float*)(ws + 32768);
  float* oatt  = (float*)(ws + 49152);
  float* katt  = (float*)(ws + 65536);
  float* sc    = (float*)(ws + 65792);   // 16KB -> ends 82176
  float* zerop = (float*)(ws + 82176);   // 1KB zero page -> ends 83200
  float* sums  = (float*)(ws + 83200);   // 2KB BN accumulators
  unsigned short* xtr = (unsigned short*)(ws + 262144);                // 32MB
  unsigned short* agg = (unsigned short*)(ws + 262144 + 33554432);     // 18.9MB
  // psum/pmax alias the agg region (consumed by k_tiny before k_agg writes agg)
  float* psum = (float*)(ws + 262144 + 33554432);                      // 1MB
  float* pmax = (float*)(ws + 262144 + 33554432 + 1048576);            // 1MB
  float* z = (float*)d_out;

  k_pre<<<dim3(64, 4, 16), 256, 0, stream>>>(x, xtr, psum, pmax);
  k_tiny<<<16, 256, 0, stream>>>(psum, pmax, aw3, Wout, Wk, lw3, lbia, mw1, mw2,
                                 inatt, oatt, katt, sc, sums, zerop);
  k_agg<<<256, 256, 0, stream>>>(ede, katt, inatt, agg);
  k_conv<<<256, 512, 0, stream>>>(agg, xtr, x, oatt, sc, zerop, sums, z);
  k_apply<<<4096, 256, 0, stream>>>(z, sums, gamma, beta);
}